// Round 12
// baseline (193.328 us; speedup 1.0000x reference)
//
#include <hip/hip_runtime.h>
#include <hip/hip_bf16.h>

// GCN layer. Algebra: A2[n] = A1[n].*x[n], so only A1 (+cnt) is edge-accumulated.
//   out[n] = LeakyReLU(A1@W1^T + (A1.*x[n])@W2^T + c*(b1+b2), 0.2)
//
// Pipeline (4 kernels, R20):
//   1. prep_init: bf16 node table + gcur[b] = b*BCAP  (R15 form)
//   2. part_scatter (1024 thr, 4096 edges/block): LDS bin-sort by bucket
//      (dst>>7, NB=782 bins), ONE global atomicAdd per non-empty bucket
//      reserves a CONTIGUOUS run, runs dumped coalesced.  (R15 form)
//   3. accum_fused (R20): one 256-thr block per 32-NODE QUARTER-BUCKET,
//      grid 4*NB=3128. Lever = concurrency, the only thing that has moved
//      accum (R17->R18: occ 27->47.5%, 68.5->62.4). R19 proved Phase A
//      window re-reads are L2-absorbed (FETCH flat when halved) => extra
//      passes are free; Phase B gather stream is the floor and scales with
//      resident waves. SCAP=768 (mean 512+11sigma), LDS 12.3KB -> 13
//      blocks/CU cap; grid 12.2/CU -> occupancy ceiling = 32-wave HW cap.
//      Phase A: 1 global pass, filter quarter, compact via ds_add_rtn +
//      32-bin hist; wave-0 shfl scan; LDS->LDS scatter. Phase B: R15's
//      proven single-loc loop, 8 locs/wave. R13/R14 LESSON: LDS FP atomics
//      ~236cyc un-pipelined -- never stream through them.
//   4. node_gemm (R10): MFMA 16x16x32 bf16, out = Acat @ Wcat^T.
//
// Record: uint2{ src, (dst<<15) | q15(norm) }  (dst<131072 fits 17 bits)
// ws (4B units): cnt[N] | gcur[NB] | epk[NB*BCAP*2] | xbf[N*32]
// xbf packing: word w of node n = bf16(x[w+32])<<16 | bf16(x[w])
// Acat packing (64 u32 words/row, k-permuted): lane sl (0..7) owns
//   words 4sl..4sl+3   = pk(a1[4sl],a1[4sl+1]) pk(a1[4sl+2],a1[4sl+3])
//                        pk(a1[4sl+32],..33)   pk(a1[4sl+34],..35)
//   words 32+4sl..+3   = same with a2 = a1.*xd
// Wcat LDS mirrors this k-order; word j<32 from W1, j>=32 from W2.

#define CHUNK 4096
#define NBMAX 1024
#define BCAP  2304   // per-128-node-bucket capacity: mean 2046, sigma 45 -> +5.7σ
#define SCAP  768    // per-32-node quarter-bucket: mean 512, sigma ~23 -> +11σ

typedef __attribute__((ext_vector_type(8))) short short8v;   // 8 bf16
typedef __attribute__((ext_vector_type(4))) float f32x4;
union U4S8 { uint4 u; short8v s; };

__device__ __forceinline__ unsigned int f2bf(float f) {
    unsigned int u = __float_as_uint(f);
    u += 0x7fffu + ((u >> 16) & 1u);
    return u >> 16;
}
__device__ __forceinline__ unsigned int pkbf(float lo, float hi) {
    return (f2bf(hi) << 16) | f2bf(lo);
}

__global__ __launch_bounds__(256) void prep_init_kernel(
    const float* __restrict__ srcEmb, const float* __restrict__ dstEmb,
    unsigned int* __restrict__ xbf, int* __restrict__ gcur,
    int Ntot, int n_src, int NB)
{
    int i = blockIdx.x * 256 + threadIdx.x;
    if (i < NB) gcur[i] = i * BCAP;
    if (i >= Ntot * 32) return;
    int n = i >> 5, w = i & 31;
    const float* row = (n < n_src) ? srcEmb + (size_t)n * 64
                                   : dstEmb + (size_t)(n - n_src) * 64;
    xbf[i] = (f2bf(row[w + 32]) << 16) | f2bf(row[w]);
}

// 1024 threads, 4096 edges/block (4 per thread, held in registers). R15 form.
__global__ __launch_bounds__(1024) void part_scatter_kernel(
    const int* __restrict__ es, const int* __restrict__ ed,
    const float* __restrict__ norm, int* __restrict__ gcur,
    uint2* __restrict__ epk, int E, int NB)
{
    __shared__ int   bcnt[NBMAX];    // counts -> local cursors
    __shared__ int   lstart[NBMAX];  // local run starts
    __shared__ int   gbase[NBMAX];   // reserved global run bases
    __shared__ int   sc[NBMAX];
    __shared__ uint2 sorted[CHUNK];  // 32 KB

    int t  = threadIdx.x;
    int e0 = blockIdx.x * CHUNK;

    bcnt[t] = 0;
    __syncthreads();

    // pass 1: histogram by bucket; dst held in registers for pass 2
    int dreg[4];
    #pragma unroll
    for (int k = 0; k < 4; ++k) {
        int e = e0 + t + k * 1024;
        dreg[k] = (e < E) ? ed[e] : -1;
        if (dreg[k] >= 0) atomicAdd(&bcnt[dreg[k] >> 7], 1);
    }
    __syncthreads();

    // full-block scan over NBMAX bins (one bin per thread) + run reservation
    int c = (t < NB) ? bcnt[t] : 0;
    sc[t] = c;
    __syncthreads();
    for (int off = 1; off < NBMAX; off <<= 1) {
        int x = 0;
        if (t >= off) x = sc[t - off];
        __syncthreads();
        if (t >= off) sc[t] += x;
        __syncthreads();
    }
    int ex = sc[t] - c;
    lstart[t] = ex;
    bcnt[t]   = ex;                 // becomes local cursor
    if (c > 0) gbase[t] = atomicAdd(&gcur[t], c);
    __syncthreads();

    // pass 2: place records into LDS sorted-by-bucket order
    #pragma unroll
    for (int k = 0; k < 4; ++k) {
        int e = e0 + t + k * 1024;
        if (dreg[k] >= 0) {
            unsigned int q = (unsigned int)(norm[e] * 32767.f + 0.5f);
            if (q > 32767u) q = 32767u;
            int lp = atomicAdd(&bcnt[dreg[k] >> 7], 1);
            uint2 r; r.x = (unsigned int)es[e];
            r.y = ((unsigned int)dreg[k] << 15) | q;
            sorted[lp] = r;
        }
    }
    __syncthreads();

    // pass 3: coalesced run dump
    int total = E - e0; if (total > CHUNK) total = CHUNK;
    for (int i = t; i < total; i += 1024) {
        uint2 r = sorted[i];
        int b = (int)(r.y >> 22);                 // dst >> 7
        int gpos = gbase[b] + (i - lstart[b]);
        if (gpos < (b + 1) * BCAP)                // overflow guard
            epk[gpos] = r;
    }
}

// R20: one 256-thread block (4 waves) per 32-node quarter-bucket.
// b = blk>>2, qh = blk&3; handles locs [qh*32, qh*32+32) of bucket b.
// Phase A1: ONE coalesced global pass over the bucket window; this
//   quarter's records compact into raw[] (ds_add_rtn cursor) + 32-bin hist.
// Phase A2: wave-0 shfl scan (32 lanes). Phase A3: LDS->LDS scatter.
// Phase B: wave wv handles locs wv + 4*li (li=0..7), R15 inner loop.
__global__ __launch_bounds__(256) void accum_fused_kernel(
    const unsigned int* __restrict__ xbf,
    const int* __restrict__ gcur, const uint2* __restrict__ epk,
    unsigned int* __restrict__ Acat, float* __restrict__ cnt, int Ntot)
{
    __shared__ uint2 raw[SCAP];     // 6.1 KB compacted (unsorted, this quarter)
    __shared__ uint2 srt[SCAP];     // 6.1 KB sorted by loc
    __shared__ int   bh[32];
    __shared__ int   offs[33];
    __shared__ int   ccur;

    int blk = blockIdx.x;
    int b   = blk >> 2, qh = blk & 3;
    int t   = threadIdx.x;
    int base    = b * BCAP;
    int total   = gcur[b] - base;
    if (total > BCAP) total = BCAP;
    int locbase = qh << 5;

    if (t < 32) bh[t] = 0;
    if (t == 0) ccur = 0;
    __syncthreads();

    // -------- Phase A1: single global pass, compact + hist --------
    for (int i = t; i < total; i += 256) {
        uint2 r = epk[base + i];
        int loc = (int)((r.y >> 15) & 127);
        if ((loc >> 5) == qh) {
            atomicAdd(&bh[loc & 31], 1);          // INT LDS atomic: fast
            int pos = atomicAdd(&ccur, 1);        // ds_add_rtn_u32
            if (pos < SCAP) raw[pos] = r;
        }
    }
    __syncthreads();

    // -------- Phase A2: wave-0 scan of 32 bins --------
    if (t < 32) {
        int c = bh[t];
        int p = c;
        #pragma unroll
        for (int off = 1; off < 32; off <<= 1) {
            int x = __shfl_up(p, off, 32);
            if (t >= off) p += x;
        }
        int ex = p - c;
        if (ex > SCAP) ex = SCAP;   // overflow clamp (11-sigma guard)
        int en = p;
        if (en > SCAP) en = SCAP;
        offs[t] = ex;
        if (t == 31) offs[32] = en;
        bh[t] = ex;                 // running cursor
    }
    __syncthreads();

    // -------- Phase A3: LDS->LDS scatter by loc --------
    int nmine = ccur; if (nmine > SCAP) nmine = SCAP;
    for (int i = t; i < nmine; i += 256) {
        uint2 r = raw[i];
        int pos = atomicAdd(&bh[(r.y >> 15) & 31], 1);
        if (pos < SCAP) srt[pos] = r;
    }
    __syncthreads();

    // -------- Phase B: register accumulation (R15 proven loop) --------
    int lane = t & 63;
    int wv   = t >> 6;
    int sl   = lane & 7;
    int g    = lane >> 3;

    for (int li = 0; li < 8; ++li) {
        int l32 = wv + (li << 2);           // 0..31 across 4 waves x 8
        int n   = b * 128 + locbase + l32;
        int s0  = offs[l32];
        int s1  = offs[l32 + 1];

        float ax0 = 0.f, ax1 = 0.f, ax2 = 0.f, ax3 = 0.f;
        float ay0 = 0.f, ay1 = 0.f, ay2 = 0.f, ay3 = 0.f;
        float c = 0.f;

        for (int bs2 = s0; bs2 < s1; bs2 += 64) {
            int m = s1 - bs2; if (m > 64) m = 64;
            unsigned int px = 0u, py = 0u;        // 0 => w=0 (src 0 harmless)
            if (lane < m) { uint2 pk = srt[bs2 + lane]; px = pk.x; py = pk.y; }
            for (int k = 0; k < m; k += 16) {
                unsigned int sx0 = __shfl(px, k + g);
                unsigned int sy0 = __shfl(py, k + g);
                unsigned int sx1 = __shfl(px, k + 8 + g);
                unsigned int sy1 = __shfl(py, k + 8 + g);
                uint4 u0 = *(const uint4*)(xbf + (size_t)sx0 * 32 + 4 * sl);
                uint4 u1 = *(const uint4*)(xbf + (size_t)sx1 * 32 + 4 * sl);
                float w0 = (float)(sy0 & 0x7fffu) * (1.f / 32767.f);
                float w1 = (float)(sy1 & 0x7fffu) * (1.f / 32767.f);
                ax0 = fmaf(w0, __uint_as_float(u0.x << 16), ax0);
                ax1 = fmaf(w0, __uint_as_float(u0.y << 16), ax1);
                ax2 = fmaf(w0, __uint_as_float(u0.z << 16), ax2);
                ax3 = fmaf(w0, __uint_as_float(u0.w << 16), ax3);
                ay0 = fmaf(w0, __uint_as_float(u0.x & 0xffff0000u), ay0);
                ay1 = fmaf(w0, __uint_as_float(u0.y & 0xffff0000u), ay1);
                ay2 = fmaf(w0, __uint_as_float(u0.z & 0xffff0000u), ay2);
                ay3 = fmaf(w0, __uint_as_float(u0.w & 0xffff0000u), ay3);
                c += w0;
                ax0 = fmaf(w1, __uint_as_float(u1.x << 16), ax0);
                ax1 = fmaf(w1, __uint_as_float(u1.y << 16), ax1);
                ax2 = fmaf(w1, __uint_as_float(u1.z << 16), ax2);
                ax3 = fmaf(w1, __uint_as_float(u1.w << 16), ax3);
                ay0 = fmaf(w1, __uint_as_float(u1.x & 0xffff0000u), ay0);
                ay1 = fmaf(w1, __uint_as_float(u1.y & 0xffff0000u), ay1);
                ay2 = fmaf(w1, __uint_as_float(u1.z & 0xffff0000u), ay2);
                ay3 = fmaf(w1, __uint_as_float(u1.w & 0xffff0000u), ay3);
                c += w1;
            }
        }

        // reduce across the 8 record-groups (lane bits 3,4,5)
        #pragma unroll
        for (int off = 8; off < 64; off <<= 1) {
            ax0 += __shfl_xor(ax0, off); ax1 += __shfl_xor(ax1, off);
            ax2 += __shfl_xor(ax2, off); ax3 += __shfl_xor(ax3, off);
            ay0 += __shfl_xor(ay0, off); ay1 += __shfl_xor(ay1, off);
            ay2 += __shfl_xor(ay2, off); ay3 += __shfl_xor(ay3, off);
            c   += __shfl_xor(c,   off);
        }

        if (g == 0 && n < Ntot) {
            // xd for this node's own dims: word 4sl+i = (x[4sl+i], x[4sl+i+32])
            uint4 xv = *(const uint4*)(xbf + (size_t)n * 32 + 4 * sl);
            float xl0 = __uint_as_float(xv.x << 16);
            float xl1 = __uint_as_float(xv.y << 16);
            float xl2 = __uint_as_float(xv.z << 16);
            float xl3 = __uint_as_float(xv.w << 16);
            float xh0 = __uint_as_float(xv.x & 0xffff0000u);
            float xh1 = __uint_as_float(xv.y & 0xffff0000u);
            float xh2 = __uint_as_float(xv.z & 0xffff0000u);
            float xh3 = __uint_as_float(xv.w & 0xffff0000u);

            uint4 w0;
            w0.x = pkbf(ax0, ax1);
            w0.y = pkbf(ax2, ax3);
            w0.z = pkbf(ay0, ay1);
            w0.w = pkbf(ay2, ay3);
            uint4 w1;
            w1.x = pkbf(ax0 * xl0, ax1 * xl1);
            w1.y = pkbf(ax2 * xl2, ax3 * xl3);
            w1.z = pkbf(ay0 * xh0, ay1 * xh1);
            w1.w = pkbf(ay2 * xh2, ay3 * xh3);
            *(uint4*)(Acat + (size_t)n * 64 + 4 * sl)      = w0;
            *(uint4*)(Acat + (size_t)n * 64 + 32 + 4 * sl) = w1;
            if (sl == 0) cnt[n] = c;
        }
    }
}

// MFMA gemm: 64 rows/block (4 waves x 16), out = Acat @ Wcat^T + cnt*(b1+b2),
// LeakyReLU. Wcat LDS built with the same k-permutation as Acat packing.
// In-place over d_out: each wave reads only its own 16 rows before writing.
__global__ __launch_bounds__(256) void node_gemm_kernel(
    const unsigned int* __restrict__ Acat, const float* __restrict__ cnt,
    const float* __restrict__ W1, const float* __restrict__ b1,
    const float* __restrict__ W2, const float* __restrict__ b2,
    float* __restrict__ out, int Ntot)
{
    __shared__ unsigned int wlds[64 * 68];   // [o][68 words], 272B row = 17x16B

    int t     = threadIdx.x;
    int lane  = t & 63;
    int wv    = t >> 6;
    int base  = blockIdx.x * 64;
    int row16 = lane & 15;    // A-row within 16-tile / D-col within 16-tile
    int q     = lane >> 4;    // k-block 0..3

    // A-frags: 4 x 16B global loads per lane (clamped rows; guarded on store)
    int arow = base + wv * 16 + row16;
    if (arow >= Ntot) arow = Ntot - 1;
    const uint4* ap = (const uint4*)(Acat + (size_t)arow * 64);
    uint4 af[4];
    #pragma unroll
    for (int s = 0; s < 4; ++s) af[s] = ap[s * 4 + q];

    // Build Wcat LDS (bf16-pair words, k-order mirrors Acat lane packing)
    for (int i = t; i < 64 * 64; i += 256) {
        int o = i >> 6, j = i & 63;
        int jj = j & 31, sl = jj >> 2, tt = jj & 3;
        int d0 = 4 * sl + ((tt & 1) << 1) + ((tt & 2) ? 32 : 0);
        const float* wsrc = (j < 32) ? W1 : W2;
        wlds[o * 68 + j] = pkbf(wsrc[o * 64 + d0], wsrc[o * 64 + d0 + 1]);
    }

    // acc init: cnt[row]*(b1[col]+b2[col]) (fp32-exact bias path)
    float cload[4];
    #pragma unroll
    for (int r = 0; r < 4; ++r) {
        int grow = base + wv * 16 + q * 4 + r;
        cload[r] = cnt[grow < Ntot ? grow : (Ntot - 1)];
    }
    f32x4 acc[4];
    #pragma unroll
    for (int j = 0; j < 4; ++j) {
        int col = j * 16 + row16;
        float bs = b1[col] + b2[col];
        #pragma unroll
        for (int r = 0; r < 4; ++r) acc[j][r] = cload[r] * bs;
    }
    __syncthreads();

    #pragma unroll
    for (int s = 0; s < 4; ++s) {
        U4S8 a; a.u = af[s];
        #pragma unroll
        for (int j = 0; j < 4; ++j) {
            int o = j * 16 + row16;
            U4S8 bb; bb.u = *(const uint4*)(wlds + o * 68 + s * 16 + q * 4);
            acc[j] = __builtin_amdgcn_mfma_f32_16x16x32_bf16(
                a.s, bb.s, acc[j], 0, 0, 0);
        }
    }

    // epilogue: D row=(lane>>4)*4+r, col=j*16+(lane&15)
    #pragma unroll
    for (int r = 0; r < 4; ++r) {
        int grow = base + wv * 16 + q * 4 + r;
        if (grow < Ntot) {
            #pragma unroll
            for (int j = 0; j < 4; ++j) {
                float a = acc[j][r];
                out[(size_t)grow * 64 + j * 16 + row16] = (a > 0.f) ? a : 0.2f * a;
            }
        }
    }
}

extern "C" void kernel_launch(void* const* d_in, const int* in_sizes, int n_in,
                              void* d_out, int out_size, void* d_ws, size_t ws_size,
                              hipStream_t stream) {
    const float* srcEmb = (const float*)d_in[0];
    const float* dstEmb = (const float*)d_in[1];
    const float* norm   = (const float*)d_in[2];
    const float* W1     = (const float*)d_in[3];
    const float* b1     = (const float*)d_in[4];
    const float* W2     = (const float*)d_in[5];
    const float* b2     = (const float*)d_in[6];
    const int*   es     = (const int*)d_in[7];
    const int*   ed     = (const int*)d_in[8];

    const int n_src = in_sizes[0] / 64;
    const int n_dst = in_sizes[1] / 64;
    const int Ntot  = n_src + n_dst;
    const int E     = in_sizes[7];
    const int NB    = (Ntot + 127) >> 7;     // 128-node buckets (NB <= 1024)

    // Workspace carve-up (4-byte units); epk/xbf 16B-aligned (dwordx4 gathers).
    float* cnt      = (float*)d_ws;                          // Ntot
    int*   gcur     = (int*)(cnt + Ntot);                    // NB
    size_t off4     = (size_t)Ntot + NB;
    off4 = (off4 + 3) & ~(size_t)3;
    uint2* epk      = (uint2*)((float*)d_ws + off4);         // NB*BCAP uint2
    unsigned int* xbf = (unsigned int*)(epk + (size_t)NB * BCAP); // Ntot*32
    unsigned int* Acat = (unsigned int*)d_out;               // Ntot*64 words (bf16 x128)

    prep_init_kernel<<<(Ntot * 32 + 255) / 256, 256, 0, stream>>>(
        srcEmb, dstEmb, xbf, gcur, Ntot, n_src, NB);

    part_scatter_kernel<<<(E + CHUNK - 1) / CHUNK, 1024, 0, stream>>>(
        es, ed, norm, gcur, epk, E, NB);

    accum_fused_kernel<<<NB * 4, 256, 0, stream>>>(
        xbf, gcur, epk, Acat, cnt, Ntot);

    node_gemm_kernel<<<(Ntot + 63) / 64, 256, 0, stream>>>(
        Acat, cnt, W1, b1, W2, b2, (float*)d_out, Ntot);
}

// Round 13
// 184.634 us; speedup vs baseline: 1.0471x; 1.0471x over previous
//
#include <hip/hip_runtime.h>
#include <hip/hip_bf16.h>

// GCN layer. Algebra: A2[n] = A1[n].*x[n], so only A1 (+cnt) is edge-accumulated.
//   out[n] = LeakyReLU(A1@W1^T + (A1.*x[n])@W2^T + c*(b1+b2), 0.2)
//
// Pipeline (4 kernels, R21):
//   1. prep_init: INT16-q7 node table (xbf word = q[w+32]<<16 | q[w],
//      q = round(x*128)) + gcur[b] = b*BCAP.
//   2. part_scatter: unchanged R15 form.
//   3. accum_fused (R21): one 256-thr block per 32-node quarter-bucket,
//      grid 4*NB. R20 lesson: +28% occupancy -> 0% => gather path is
//      per-CU miss-queue bound (12.5K misses/CU x ~550cyc / ~64 MSHR
//      ~= the 45us Phase B floor). Two levers:
//      (a) INT fixed-point LDS scatter: group-per-record, 8 int muls +
//          8 int atomicAdd (ds_add_u32 no-rtn -- the PROVEN-fast hist
//          primitive, NOT R13's float-CAS trap) into acc[32][65] int.
//          Deletes shfl staging, per-loc loops, xor tree, divergence:
//          ~4 wave-instr/record vs ~20. Overflow: 50*32767*704 = 1.15e9
//          < 2^31. Precision: q7 err <=0.0039 abs ~ bf16 class (passed
//          all session).
//      (b) slab-ordered gathers: Phase A counting-sorts the quarter's
//          records by src>>14 (8 x 2MB slabs). All blocks co-resident &
//          in lockstep => chip-wide gathers focus on 2MB (fits 4MB/XCD
//          L2) => misses L3(~600cy) -> L2(~200cy). FETCH_SIZE is the
//          diagnostic: drops if coherence works.
//   4. node_gemm (R10): MFMA 16x16x32 bf16, out = Acat @ Wcat^T.
//
// Record: uint2{ src, (dst<<15) | q15(norm) }  (dst<131072 fits 17 bits)
// ws (4B units): cnt[N] | gcur[NB] | epk[NB*BCAP*2] | xbf[N*32]
// xbf packing (R21): word w of node n = (int16 q7(x[w+32]))<<16 | q7(x[w])
// Acat packing (64 u32 words/row, k-permuted): lane sl (0..7) owns
//   words 4sl..4sl+3   = pk(a1[4sl],a1[4sl+1]) pk(a1[4sl+2],a1[4sl+3])
//                        pk(a1[4sl+32],..33)   pk(a1[4sl+34],..35)
//   words 32+4sl..+3   = same with a2 = a1.*xd
// Wcat LDS mirrors this k-order; word j<32 from W1, j>=32 from W2.

#define CHUNK 4096
#define NBMAX 1024
#define BCAP  2304   // per-128-node-bucket capacity: mean 2046, sigma 45 -> +5.7σ
#define SCAP  768    // per-32-node quarter-bucket: mean 512, sigma ~23 -> +11σ
#define NSLAB 8
#define SLBSH 14     // src>>14 -> 16384-node (2 MB) slabs

typedef __attribute__((ext_vector_type(8))) short short8v;   // 8 bf16
typedef __attribute__((ext_vector_type(4))) float f32x4;
union U4S8 { uint4 u; short8v s; };

__device__ __forceinline__ unsigned int f2bf(float f) {
    unsigned int u = __float_as_uint(f);
    u += 0x7fffu + ((u >> 16) & 1u);
    return u >> 16;
}
__device__ __forceinline__ unsigned int pkbf(float lo, float hi) {
    return (f2bf(hi) << 16) | f2bf(lo);
}

__global__ __launch_bounds__(256) void prep_init_kernel(
    const float* __restrict__ srcEmb, const float* __restrict__ dstEmb,
    unsigned int* __restrict__ xbf, int* __restrict__ gcur,
    int Ntot, int n_src, int NB)
{
    int i = blockIdx.x * 256 + threadIdx.x;
    if (i < NB) gcur[i] = i * BCAP;
    if (i >= Ntot * 32) return;
    int n = i >> 5, w = i & 31;
    const float* row = (n < n_src) ? srcEmb + (size_t)n * 64
                                   : dstEmb + (size_t)(n - n_src) * 64;
    int qlo = (int)rintf(row[w] * 128.f);
    int qhi = (int)rintf(row[w + 32] * 128.f);
    qlo = qlo > 32767 ? 32767 : (qlo < -32767 ? -32767 : qlo);
    qhi = qhi > 32767 ? 32767 : (qhi < -32767 ? -32767 : qhi);
    xbf[i] = ((unsigned int)qhi << 16) | ((unsigned int)qlo & 0xffffu);
}

// 1024 threads, 4096 edges/block (4 per thread, held in registers). R15 form.
__global__ __launch_bounds__(1024) void part_scatter_kernel(
    const int* __restrict__ es, const int* __restrict__ ed,
    const float* __restrict__ norm, int* __restrict__ gcur,
    uint2* __restrict__ epk, int E, int NB)
{
    __shared__ int   bcnt[NBMAX];    // counts -> local cursors
    __shared__ int   lstart[NBMAX];  // local run starts
    __shared__ int   gbase[NBMAX];   // reserved global run bases
    __shared__ int   sc[NBMAX];
    __shared__ uint2 sorted[CHUNK];  // 32 KB

    int t  = threadIdx.x;
    int e0 = blockIdx.x * CHUNK;

    bcnt[t] = 0;
    __syncthreads();

    // pass 1: histogram by bucket; dst held in registers for pass 2
    int dreg[4];
    #pragma unroll
    for (int k = 0; k < 4; ++k) {
        int e = e0 + t + k * 1024;
        dreg[k] = (e < E) ? ed[e] : -1;
        if (dreg[k] >= 0) atomicAdd(&bcnt[dreg[k] >> 7], 1);
    }
    __syncthreads();

    // full-block scan over NBMAX bins (one bin per thread) + run reservation
    int c = (t < NB) ? bcnt[t] : 0;
    sc[t] = c;
    __syncthreads();
    for (int off = 1; off < NBMAX; off <<= 1) {
        int x = 0;
        if (t >= off) x = sc[t - off];
        __syncthreads();
        if (t >= off) sc[t] += x;
        __syncthreads();
    }
    int ex = sc[t] - c;
    lstart[t] = ex;
    bcnt[t]   = ex;                 // becomes local cursor
    if (c > 0) gbase[t] = atomicAdd(&gcur[t], c);
    __syncthreads();

    // pass 2: place records into LDS sorted-by-bucket order
    #pragma unroll
    for (int k = 0; k < 4; ++k) {
        int e = e0 + t + k * 1024;
        if (dreg[k] >= 0) {
            unsigned int q = (unsigned int)(norm[e] * 32767.f + 0.5f);
            if (q > 32767u) q = 32767u;
            int lp = atomicAdd(&bcnt[dreg[k] >> 7], 1);
            uint2 r; r.x = (unsigned int)es[e];
            r.y = ((unsigned int)dreg[k] << 15) | q;
            sorted[lp] = r;
        }
    }
    __syncthreads();

    // pass 3: coalesced run dump
    int total = E - e0; if (total > CHUNK) total = CHUNK;
    for (int i = t; i < total; i += 1024) {
        uint2 r = sorted[i];
        int b = (int)(r.y >> 22);                 // dst >> 7
        int gpos = gbase[b] + (i - lstart[b]);
        if (gpos < (b + 1) * BCAP)                // overflow guard
            epk[gpos] = r;
    }
}

// R21: one 256-thread block (4 waves) per 32-node quarter-bucket.
// Phase A: 2 global window passes (L2-free per R19): slab hist (8 bins,
//   filtered to quarter) -> serial scan -> scatter into srt in SLAB order.
// Phase B: group-per-record int scatter. Round = 32 records (4 waves x 8
//   groups). Per group: broadcast srt read, one dwordx4 gather, 8 int16
//   extracts, 8 muls, 8 int LDS atomicAdds into acc[loc][dim] (+cnt col 64).
// Epilogue: 256 threads = 32 locs x 8 sls; scale, pack Acat bf16.
__global__ __launch_bounds__(256) void accum_fused_kernel(
    const unsigned int* __restrict__ xbf,
    const int* __restrict__ gcur, const uint2* __restrict__ epk,
    unsigned int* __restrict__ Acat, float* __restrict__ cnt, int Ntot)
{
    __shared__ int   acc[32 * 65];  // 8.3 KB: [loc][0..63 dims, 64 = cnt]
    __shared__ uint2 srt[SCAP];     // 6.1 KB slab-ordered records
    __shared__ int   sh[NSLAB];
    __shared__ int   nmyr;

    int blk = blockIdx.x;
    int b   = blk >> 2, qh = blk & 3;
    int t   = threadIdx.x;
    int base  = b * BCAP;
    int total = gcur[b] - base;
    if (total > BCAP) total = BCAP;

    for (int i = t; i < 32 * 65; i += 256) acc[i] = 0;
    if (t < NSLAB) sh[t] = 0;
    __syncthreads();

    // Phase A pass 1: slab histogram (filtered to this quarter)
    for (int i = t; i < total; i += 256) {
        uint2 r = epk[base + i];
        int loc = (int)((r.y >> 15) & 127);
        if ((loc >> 5) == qh) atomicAdd(&sh[r.x >> SLBSH], 1);
    }
    __syncthreads();

    if (t == 0) {                   // 8-bin exclusive scan -> cursors
        int s = 0;
        #pragma unroll
        for (int k = 0; k < NSLAB; ++k) { int c0 = sh[k]; sh[k] = s; s += c0; }
        nmyr = (s > SCAP) ? SCAP : s;
    }
    __syncthreads();

    // Phase A pass 2: scatter into srt in slab order (window L2-hot)
    for (int i = t; i < total; i += 256) {
        uint2 r = epk[base + i];
        int loc = (int)((r.y >> 15) & 127);
        if ((loc >> 5) == qh) {
            int pos = atomicAdd(&sh[r.x >> SLBSH], 1);
            if (pos < SCAP) srt[pos] = r;
        }
    }
    __syncthreads();

    // Phase B: group-per-record int scatter accumulation
    int lane = t & 63;
    int wv   = t >> 6;
    int g    = lane >> 3;
    int sl   = lane & 7;
    int nr   = nmyr;
    int iters = (nr + 31) >> 5;

    for (int it = 0; it < iters; ++it) {
        int r = it * 32 + wv * 8 + g;
        unsigned int rx = 0u, ry = 0u;            // pad: wq=0, loc=0, row 0
        if (r < nr) { uint2 rc = srt[r]; rx = rc.x; ry = rc.y; }
        int wq  = (int)(ry & 0x7fffu);
        int loc = (int)((ry >> 15) & 31);
        uint4 u = *(const uint4*)(xbf + (size_t)rx * 32 + 4 * sl);
        int x0 = (int)(u.x << 16) >> 16, x4 = (int)u.x >> 16;
        int x1 = (int)(u.y << 16) >> 16, x5 = (int)u.y >> 16;
        int x2 = (int)(u.z << 16) >> 16, x6 = (int)u.z >> 16;
        int x3 = (int)(u.w << 16) >> 16, x7 = (int)u.w >> 16;
        int* a = acc + loc * 65 + 4 * sl;
        atomicAdd(a + 0,  wq * x0);
        atomicAdd(a + 1,  wq * x1);
        atomicAdd(a + 2,  wq * x2);
        atomicAdd(a + 3,  wq * x3);
        atomicAdd(a + 32, wq * x4);
        atomicAdd(a + 33, wq * x5);
        atomicAdd(a + 34, wq * x6);
        atomicAdd(a + 35, wq * x7);
        if (sl == 0) atomicAdd(acc + loc * 65 + 64, wq);
    }
    __syncthreads();

    // Epilogue: 256 threads = 32 locs x 8 word-groups
    {
        int loc = t >> 3, psl = t & 7;
        int n = b * 128 + (qh << 5) + loc;
        if (n < Ntot) {
            const float s1 = 1.f / (32767.f * 128.f);
            const int* a = acc + loc * 65 + 4 * psl;
            float ax0 = a[0]  * s1, ax1 = a[1]  * s1;
            float ax2 = a[2]  * s1, ax3 = a[3]  * s1;
            float ay0 = a[32] * s1, ay1 = a[33] * s1;
            float ay2 = a[34] * s1, ay3 = a[35] * s1;

            const float sx = 1.f / 128.f;
            uint4 xv = *(const uint4*)(xbf + (size_t)n * 32 + 4 * psl);
            float xl0 = (float)((int)(xv.x << 16) >> 16) * sx;
            float xl1 = (float)((int)(xv.y << 16) >> 16) * sx;
            float xl2 = (float)((int)(xv.z << 16) >> 16) * sx;
            float xl3 = (float)((int)(xv.w << 16) >> 16) * sx;
            float xh0 = (float)((int)xv.x >> 16) * sx;
            float xh1 = (float)((int)xv.y >> 16) * sx;
            float xh2 = (float)((int)xv.z >> 16) * sx;
            float xh3 = (float)((int)xv.w >> 16) * sx;

            uint4 w0;
            w0.x = pkbf(ax0, ax1);
            w0.y = pkbf(ax2, ax3);
            w0.z = pkbf(ay0, ay1);
            w0.w = pkbf(ay2, ay3);
            uint4 w1;
            w1.x = pkbf(ax0 * xl0, ax1 * xl1);
            w1.y = pkbf(ax2 * xl2, ax3 * xl3);
            w1.z = pkbf(ay0 * xh0, ay1 * xh1);
            w1.w = pkbf(ay2 * xh2, ay3 * xh3);
            *(uint4*)(Acat + (size_t)n * 64 + 4 * psl)      = w0;
            *(uint4*)(Acat + (size_t)n * 64 + 32 + 4 * psl) = w1;
            if (psl == 0) cnt[n] = (float)acc[loc * 65 + 64] * (1.f / 32767.f);
        }
    }
}

// MFMA gemm: 64 rows/block (4 waves x 16), out = Acat @ Wcat^T + cnt*(b1+b2),
// LeakyReLU. Wcat LDS built with the same k-permutation as Acat packing.
// In-place over d_out: each wave reads only its own 16 rows before writing.
__global__ __launch_bounds__(256) void node_gemm_kernel(
    const unsigned int* __restrict__ Acat, const float* __restrict__ cnt,
    const float* __restrict__ W1, const float* __restrict__ b1,
    const float* __restrict__ W2, const float* __restrict__ b2,
    float* __restrict__ out, int Ntot)
{
    __shared__ unsigned int wlds[64 * 68];   // [o][68 words], 272B row = 17x16B

    int t     = threadIdx.x;
    int lane  = t & 63;
    int wv    = t >> 6;
    int base  = blockIdx.x * 64;
    int row16 = lane & 15;    // A-row within 16-tile / D-col within 16-tile
    int q     = lane >> 4;    // k-block 0..3

    // A-frags: 4 x 16B global loads per lane (clamped rows; guarded on store)
    int arow = base + wv * 16 + row16;
    if (arow >= Ntot) arow = Ntot - 1;
    const uint4* ap = (const uint4*)(Acat + (size_t)arow * 64);
    uint4 af[4];
    #pragma unroll
    for (int s = 0; s < 4; ++s) af[s] = ap[s * 4 + q];

    // Build Wcat LDS (bf16-pair words, k-order mirrors Acat lane packing)
    for (int i = t; i < 64 * 64; i += 256) {
        int o = i >> 6, j = i & 63;
        int jj = j & 31, sl = jj >> 2, tt = jj & 3;
        int d0 = 4 * sl + ((tt & 1) << 1) + ((tt & 2) ? 32 : 0);
        const float* wsrc = (j < 32) ? W1 : W2;
        wlds[o * 68 + j] = pkbf(wsrc[o * 64 + d0], wsrc[o * 64 + d0 + 1]);
    }

    // acc init: cnt[row]*(b1[col]+b2[col]) (fp32-exact bias path)
    float cload[4];
    #pragma unroll
    for (int r = 0; r < 4; ++r) {
        int grow = base + wv * 16 + q * 4 + r;
        cload[r] = cnt[grow < Ntot ? grow : (Ntot - 1)];
    }
    f32x4 acc[4];
    #pragma unroll
    for (int j = 0; j < 4; ++j) {
        int col = j * 16 + row16;
        float bs = b1[col] + b2[col];
        #pragma unroll
        for (int r = 0; r < 4; ++r) acc[j][r] = cload[r] * bs;
    }
    __syncthreads();

    #pragma unroll
    for (int s = 0; s < 4; ++s) {
        U4S8 a; a.u = af[s];
        #pragma unroll
        for (int j = 0; j < 4; ++j) {
            int o = j * 16 + row16;
            U4S8 bb; bb.u = *(const uint4*)(wlds + o * 68 + s * 16 + q * 4);
            acc[j] = __builtin_amdgcn_mfma_f32_16x16x32_bf16(
                a.s, bb.s, acc[j], 0, 0, 0);
        }
    }

    // epilogue: D row=(lane>>4)*4+r, col=j*16+(lane&15)
    #pragma unroll
    for (int r = 0; r < 4; ++r) {
        int grow = base + wv * 16 + q * 4 + r;
        if (grow < Ntot) {
            #pragma unroll
            for (int j = 0; j < 4; ++j) {
                float a = acc[j][r];
                out[(size_t)grow * 64 + j * 16 + row16] = (a > 0.f) ? a : 0.2f * a;
            }
        }
    }
}

extern "C" void kernel_launch(void* const* d_in, const int* in_sizes, int n_in,
                              void* d_out, int out_size, void* d_ws, size_t ws_size,
                              hipStream_t stream) {
    const float* srcEmb = (const float*)d_in[0];
    const float* dstEmb = (const float*)d_in[1];
    const float* norm   = (const float*)d_in[2];
    const float* W1     = (const float*)d_in[3];
    const float* b1     = (const float*)d_in[4];
    const float* W2     = (const float*)d_in[5];
    const float* b2     = (const float*)d_in[6];
    const int*   es     = (const int*)d_in[7];
    const int*   ed     = (const int*)d_in[8];

    const int n_src = in_sizes[0] / 64;
    const int n_dst = in_sizes[1] / 64;
    const int Ntot  = n_src + n_dst;
    const int E     = in_sizes[7];
    const int NB    = (Ntot + 127) >> 7;     // 128-node buckets (NB <= 1024)

    // Workspace carve-up (4-byte units); epk/xbf 16B-aligned (dwordx4 gathers).
    float* cnt      = (float*)d_ws;                          // Ntot
    int*   gcur     = (int*)(cnt + Ntot);                    // NB
    size_t off4     = (size_t)Ntot + NB;
    off4 = (off4 + 3) & ~(size_t)3;
    uint2* epk      = (uint2*)((float*)d_ws + off4);         // NB*BCAP uint2
    unsigned int* xbf = (unsigned int*)(epk + (size_t)NB * BCAP); // Ntot*32
    unsigned int* Acat = (unsigned int*)d_out;               // Ntot*64 words (bf16 x128)

    prep_init_kernel<<<(Ntot * 32 + 255) / 256, 256, 0, stream>>>(
        srcEmb, dstEmb, xbf, gcur, Ntot, n_src, NB);

    part_scatter_kernel<<<(E + CHUNK - 1) / CHUNK, 1024, 0, stream>>>(
        es, ed, norm, gcur, epk, E, NB);

    accum_fused_kernel<<<NB * 4, 256, 0, stream>>>(
        xbf, gcur, epk, Acat, cnt, Ntot);

    node_gemm_kernel<<<(Ntot + 63) / 64, 256, 0, stream>>>(
        Acat, cnt, W1, b1, W2, b2, (float*)d_out, Ntot);
}